// Round 7
// baseline (624.226 us; speedup 1.0000x reference)
//
#include <hip/hip_runtime.h>
#include <math.h>

#define N_NODES 50000
#define N_EDGES 800000
#define IN_FEAT 128
#define HIDDEN 256
#define NUM_GRAPHS 128
#define NUM_CLASSES 10
#define BN_EPS 1e-5f

#define NCHUNK ((N_NODES + 255) / 256)   // 196 scan chunks

typedef __attribute__((ext_vector_type(8))) short bf16x8;
typedef __attribute__((ext_vector_type(4))) float f32x4;

__device__ __forceinline__ ushort f2bf(float f) {
    union { float f; uint u; } c; c.f = f;
    uint u = c.u;
    return (ushort)((u + 0x7FFFu + ((u >> 16) & 1u)) >> 16);   // RNE
}
__device__ __forceinline__ float bf2f(ushort h) {
    union { uint u; float f; } c; c.u = ((uint)h) << 16;
    return c.f;
}

// ---------------- CSR build ----------------
__global__ void k_count(const int* __restrict__ dst, int* __restrict__ cnt) {
    int e = blockIdx.x * 256 + threadIdx.x;
    if (e < N_EDGES) atomicAdd(&cnt[dst[e]], 1);
}

__global__ void k_count_batch(const int* __restrict__ batch, int* __restrict__ gcnt) {
    int v = blockIdx.x * 256 + threadIdx.x;
    if (v < N_NODES) atomicAdd(&gcnt[batch[v]], 1);
}

__global__ __launch_bounds__(256) void k_chunksum(const int* __restrict__ cnt,
                                                  int* __restrict__ csum) {
    int i = blockIdx.x * 256 + threadIdx.x;
    int v = (i < N_NODES) ? cnt[i] : 0;
#pragma unroll
    for (int off = 32; off; off >>= 1) v += __shfl_down(v, off, 64);
    __shared__ int ws[4];
    if ((threadIdx.x & 63) == 0) ws[threadIdx.x >> 6] = v;
    __syncthreads();
    if (threadIdx.x == 0) csum[blockIdx.x] = ws[0] + ws[1] + ws[2] + ws[3];
}

__global__ __launch_bounds__(256) void k_scanchunks(const int* __restrict__ csum,
                                                    int* __restrict__ choff) {
    __shared__ int s[256];
    int t = threadIdx.x;
    int v = (t < NCHUNK) ? csum[t] : 0;
    s[t] = v;
    __syncthreads();
#pragma unroll
    for (int off = 1; off < 256; off <<= 1) {
        int add = (t >= off) ? s[t - off] : 0;
        __syncthreads();
        s[t] += add;
        __syncthreads();
    }
    if (t < NCHUNK) choff[t] = s[t] - v;   // exclusive
}

__global__ __launch_bounds__(256) void k_apply(const int* __restrict__ cnt,
                                               const int* __restrict__ choff,
                                               int* __restrict__ rowp,
                                               int* __restrict__ cursor,
                                               float* __restrict__ dinv) {
    __shared__ int s[256];
    int t = threadIdx.x;
    int i = blockIdx.x * 256 + t;
    int c = (i < N_NODES) ? cnt[i] : 0;
    s[t] = c;
    __syncthreads();
#pragma unroll
    for (int off = 1; off < 256; off <<= 1) {
        int add = (t >= off) ? s[t - off] : 0;
        __syncthreads();
        s[t] += add;
        __syncthreads();
    }
    int incl = s[t];
    int base = choff[blockIdx.x];
    if (i < N_NODES) {
        int ex = base + incl - c;
        rowp[i] = ex;
        cursor[i] = ex;
        dinv[i] = rsqrtf(1.0f + (float)c);
        if (i == N_NODES - 1) rowp[N_NODES] = base + incl;
    }
}

__global__ void k_fill(const int* __restrict__ src, const int* __restrict__ dst,
                       int* __restrict__ cursor, int* __restrict__ col) {
    int e = blockIdx.x * 256 + threadIdx.x;
    if (e < N_EDGES) {
        int slot = atomicAdd(&cursor[dst[e]], 1);
        col[slot] = src[e];
    }
}

// ---- graph bucketing for pooling: scan gcnt -> goff; fill nlist ----
__global__ void k_scangraphs(const int* __restrict__ gcnt, int* __restrict__ goff,
                             int* __restrict__ gcur) {
    __shared__ int s[NUM_GRAPHS];
    int t = threadIdx.x;                 // 128 threads
    int v = gcnt[t];
    s[t] = v;
    __syncthreads();
#pragma unroll
    for (int off = 1; off < NUM_GRAPHS; off <<= 1) {
        int add = (t >= off) ? s[t - off] : 0;
        __syncthreads();
        s[t] += add;
        __syncthreads();
    }
    goff[t] = s[t] - v;
    gcur[t] = s[t] - v;
    if (t == NUM_GRAPHS - 1) goff[NUM_GRAPHS] = s[t];
}

__global__ void k_fillg(const int* __restrict__ batch, int* __restrict__ gcur,
                        int* __restrict__ nlist) {
    int v = blockIdx.x * 256 + threadIdx.x;
    if (v < N_NODES) {
        int slot = atomicAdd(&gcur[batch[v]], 1);
        nlist[slot] = v;
    }
}

// ---------------- prescale: p0 = bf16(x * dinv[row]) ----------------
__global__ void k_prescale(const float* __restrict__ x, const float* __restrict__ dinv,
                           ushort* __restrict__ p0) {
    int i = blockIdx.x * 256 + threadIdx.x;      // per 4 elems
    if (i < N_NODES * IN_FEAT / 4) {
        float4 v = ((const float4*)x)[i];
        float d = dinv[i / (IN_FEAT / 4)];
        ushort4 o;
        o.x = f2bf(v.x * d); o.y = f2bf(v.y * d);
        o.z = f2bf(v.z * d); o.w = f2bf(v.w * d);
        ((ushort4*)p0)[i] = o;
    }
}

// ---------------- aggregation, 2-slice XCD-partitioned ----------------
// grid = 2 * ceil(N/4); slice = blockIdx&1 (maps to XCD parity under round-robin).
// Wave handles one dst node, one half-row slice (F bytes). SL = F/8 lanes per
// edge (ushort4 each); EPW = 64/SL edges per wave-step; 4-deep unroll.
template <int F>
__global__ __launch_bounds__(256) void k_agg(const ushort* __restrict__ p,
                                             const int* __restrict__ col,
                                             const int* __restrict__ row_ptr,
                                             const float* __restrict__ dinv,
                                             ushort* __restrict__ out) {
    constexpr int SL = F / 8;         // lanes covering one slice-row
    constexpr int EPW = 64 / SL;      // edges per wave-step
    int wave = threadIdx.x >> 6;
    int lane = threadIdx.x & 63;
    int bid = blockIdx.x;
    int slice = bid & 1;
    int v = (bid >> 1) * 4 + wave;
    if (v >= N_NODES) return;
    int sub = lane / SL;              // which edge in the step
    int sl = lane % SL;
    const int c0 = slice * (F / 2) + sl * 4;
    int rp0 = row_ptr[v], rp1 = row_ptr[v + 1];
    float a0, a1, a2, a3;
    if (sub == 0) {
        ushort4 me = *(const ushort4*)(p + (size_t)v * F + c0);
        a0 = bf2f(me.x); a1 = bf2f(me.y); a2 = bf2f(me.z); a3 = bf2f(me.w);
    } else {
        a0 = a1 = a2 = a3 = 0.f;
    }
    int i = rp0;
    for (; i + 4 * EPW <= rp1; i += 4 * EPW) {
        int s0 = col[i + sub];
        int s1 = col[i + EPW + sub];
        int s2 = col[i + 2 * EPW + sub];
        int s3 = col[i + 3 * EPW + sub];
        ushort4 q0 = *(const ushort4*)(p + (size_t)s0 * F + c0);
        ushort4 q1 = *(const ushort4*)(p + (size_t)s1 * F + c0);
        ushort4 q2 = *(const ushort4*)(p + (size_t)s2 * F + c0);
        ushort4 q3 = *(const ushort4*)(p + (size_t)s3 * F + c0);
        a0 += bf2f(q0.x) + bf2f(q1.x) + bf2f(q2.x) + bf2f(q3.x);
        a1 += bf2f(q0.y) + bf2f(q1.y) + bf2f(q2.y) + bf2f(q3.y);
        a2 += bf2f(q0.z) + bf2f(q1.z) + bf2f(q2.z) + bf2f(q3.z);
        a3 += bf2f(q0.w) + bf2f(q1.w) + bf2f(q2.w) + bf2f(q3.w);
    }
    for (; i + sub < rp1; i += EPW) {
        int s = col[i + sub];
        ushort4 q = *(const ushort4*)(p + (size_t)s * F + c0);
        a0 += bf2f(q.x); a1 += bf2f(q.y); a2 += bf2f(q.z); a3 += bf2f(q.w);
    }
    // reduce across edge-subgroups (lanes with same sl, strided SL apart)
#pragma unroll
    for (int off = SL; off < 64; off <<= 1) {
        a0 += __shfl_xor(a0, off);
        a1 += __shfl_xor(a1, off);
        a2 += __shfl_xor(a2, off);
        a3 += __shfl_xor(a3, off);
    }
    if (sub == 0) {
        float d = dinv[v];
        ushort4 o;
        o.x = f2bf(a0 * d); o.y = f2bf(a1 * d); o.z = f2bf(a2 * d); o.w = f2bf(a3 * d);
        *(ushort4*)(out + (size_t)v * F + c0) = o;
    }
}

// ---------------- W repack: fp32 [K][256] -> bf16 frag layout [nt][kt][lane][8] ----------------
template <int KDIM>
__global__ void k_repackW(const float* __restrict__ W, ushort* __restrict__ Wp) {
    const int KT = KDIM / 32;
    int tid = blockIdx.x * 256 + threadIdx.x;
    if (tid >= 16 * KT * 64) return;
    int lane = tid & 63;
    int kt = (tid >> 6) % KT;
    int nt = (tid >> 6) / KT;
    int n = nt * 16 + (lane & 15);
    int kb = kt * 32 + (lane >> 4) * 8;
    ushort o[8];
#pragma unroll
    for (int j = 0; j < 8; ++j) o[j] = f2bf(W[(size_t)(kb + j) * HIDDEN + n]);
    ushort4* dst = (ushort4*)(Wp + (size_t)tid * 8);
    dst[0] = make_ushort4(o[0], o[1], o[2], o[3]);
    dst[1] = make_ushort4(o[4], o[5], o[6], o[7]);
}

// ---------------- MFMA GEMM: out = epi(A @ W + bias), bf16 in/out, fp32 acc ----------------
// EPI: 0 = BN+relu then *dinv ; 1 = relu then *dinv ; 2 = relu (plain)
template <int KDIM, int EPI>
__global__ __launch_bounds__(256) void k_mgemm(const ushort* __restrict__ A,
                                               const ushort* __restrict__ Wp,
                                               const float* __restrict__ bias,
                                               const float* __restrict__ gamma,
                                               const float* __restrict__ beta,
                                               const float* __restrict__ mean,
                                               const float* __restrict__ var,
                                               const float* __restrict__ dinv,
                                               ushort* __restrict__ out) {
    const int KT = KDIM / 32;
    int t = threadIdx.x;
    int wv = t >> 6, lane = t & 63;
    int row0 = blockIdx.x * 64 + wv * 16;
    int g = lane >> 4, r16 = lane & 15;
    int arow = row0 + r16;
    if (arow >= N_NODES) arow = N_NODES - 1;   // safe load; store guarded

    f32x4 acc[16];
#pragma unroll
    for (int nt = 0; nt < 16; ++nt) acc[nt] = (f32x4){0.f, 0.f, 0.f, 0.f};

    const ushort* aptr = A + (size_t)arow * KDIM + g * 8;
    for (int kt = 0; kt < KT; ++kt) {
        bf16x8 af = *(const bf16x8*)(aptr + kt * 32);
#pragma unroll
        for (int nt = 0; nt < 16; ++nt) {
            bf16x8 bfv = *(const bf16x8*)(Wp + ((size_t)(nt * KT + kt) * 64 + lane) * 8);
            acc[nt] = __builtin_amdgcn_mfma_f32_16x16x32_bf16(af, bfv, acc[nt], 0, 0, 0);
        }
    }

    // epilogue: lane covers rows row0+g*4+r (r=0..3), col nt*16+r16
    int rowb = row0 + g * 4;
    float dv[4];
#pragma unroll
    for (int r = 0; r < 4; ++r) {
        int grow = rowb + r;
        dv[r] = 1.f;
        if (EPI != 2 && grow < N_NODES) dv[r] = dinv[grow];
    }
#pragma unroll
    for (int nt = 0; nt < 16; ++nt) {
        int colc = nt * 16 + r16;
        float bi = bias[colc];
        float sc = 1.f, sh = 0.f;
        if constexpr (EPI == 0) {
            float s = gamma[colc] * rsqrtf(var[colc] + BN_EPS);
            sc = s; sh = beta[colc] - mean[colc] * s;
        }
#pragma unroll
        for (int r = 0; r < 4; ++r) {
            int grow = rowb + r;
            if (grow < N_NODES) {
                float y = acc[nt][r] + bi;
                if constexpr (EPI == 0) y = y * sc + sh;
                y = fmaxf(y, 0.f);
                y *= dv[r];
                out[(size_t)grow * HIDDEN + colc] = f2bf(y);
            }
        }
    }
}

// ---------------- pooling: segment-sum over graph-sorted node list ----------------
// grid = NUM_GRAPHS * 2 (col halves); block = 8 waves; lane owns 2 cols.
__global__ __launch_bounds__(512) void k_pool2(const ushort* __restrict__ h,
                                               const int* __restrict__ nlist,
                                               const int* __restrict__ goff,
                                               float* __restrict__ sums) {
    int g = blockIdx.x >> 1, half = blockIdx.x & 1;
    int lo = goff[g], hi = goff[g + 1];
    int w = threadIdx.x >> 6, l = threadIdx.x & 63;
    const ushort* hp = h + half * 128 + l * 2;
    float a0 = 0.f, a1 = 0.f;
    int i = lo + w;
    for (; i + 24 < hi; i += 32) {
        int v0 = nlist[i], v1 = nlist[i + 8], v2 = nlist[i + 16], v3 = nlist[i + 24];
        ushort2 q0 = *(const ushort2*)(hp + (size_t)v0 * HIDDEN);
        ushort2 q1 = *(const ushort2*)(hp + (size_t)v1 * HIDDEN);
        ushort2 q2 = *(const ushort2*)(hp + (size_t)v2 * HIDDEN);
        ushort2 q3 = *(const ushort2*)(hp + (size_t)v3 * HIDDEN);
        a0 += bf2f(q0.x) + bf2f(q1.x) + bf2f(q2.x) + bf2f(q3.x);
        a1 += bf2f(q0.y) + bf2f(q1.y) + bf2f(q2.y) + bf2f(q3.y);
    }
    for (; i < hi; i += 8) {
        int v = nlist[i];
        ushort2 q = *(const ushort2*)(hp + (size_t)v * HIDDEN);
        a0 += bf2f(q.x); a1 += bf2f(q.y);
    }
    __shared__ float red[8][128];
    red[w][l * 2] = a0;
    red[w][l * 2 + 1] = a1;
    __syncthreads();
    int t = threadIdx.x;
    if (t < 128) {
        float s = red[0][t] + red[1][t] + red[2][t] + red[3][t] +
                  red[4][t] + red[5][t] + red[6][t] + red[7][t];
        sums[(size_t)g * HIDDEN + half * 128 + t] = s;
    }
}

// ---------------- logits + log_softmax per graph ----------------
__global__ __launch_bounds__(256) void k_logits(const float* __restrict__ sums,
                                                const int* __restrict__ gcnt,
                                                const float* __restrict__ W2,
                                                const float* __restrict__ b2,
                                                float* __restrict__ outp) {
    __shared__ float pooled[HIDDEN];
    int g = blockIdx.x;
    int t = threadIdx.x;
    float inv = 1.0f / fmaxf((float)gcnt[g], 1.0f);
    pooled[t] = sums[(size_t)g * HIDDEN + t] * inv;
    __syncthreads();
    if (t < 64) {
        float lg = -INFINITY;
        if (t < NUM_CLASSES) {
            lg = b2[t];
            for (int k = 0; k < HIDDEN; ++k) lg += pooled[k] * W2[k * NUM_CLASSES + t];
        }
        float m = lg;
        for (int off = 1; off < 16; off <<= 1) m = fmaxf(m, __shfl_xor(m, off));
        float e = (t < 16) ? expf(lg - m) : 0.f;
        float ssum = e;
        for (int off = 1; off < 16; off <<= 1) ssum += __shfl_xor(ssum, off);
        if (t < NUM_CLASSES) outp[g * NUM_CLASSES + t] = lg - m - logf(ssum);
    }
}

extern "C" void kernel_launch(void* const* d_in, const int* in_sizes, int n_in,
                              void* d_out, int out_size, void* d_ws, size_t ws_size,
                              hipStream_t stream) {
    const float* x     = (const float*)d_in[0];
    const int*   ei    = (const int*)d_in[1];
    const int*   batch = (const int*)d_in[2];
    const float* W1    = (const float*)d_in[3];
    const float* b1    = (const float*)d_in[4];
    const float* gamma = (const float*)d_in[5];
    const float* beta  = (const float*)d_in[6];
    const float* rmean = (const float*)d_in[7];
    const float* rvar  = (const float*)d_in[8];
    const float* Wsp   = (const float*)d_in[9];
    const float* bsp   = (const float*)d_in[10];
    const float* W2    = (const float*)d_in[11];
    const float* b2    = (const float*)d_in[12];
    float* out = (float*)d_out;

    char* w = (char*)d_ws;
    size_t off = 0;
    auto alloc = [&](size_t bytes) -> void* {
        void* p = w + off;
        off = (off + bytes + 255) & ~(size_t)255;
        return p;
    };
    int*    cnt    = (int*)alloc((size_t)N_NODES * 4);
    int*    gcnt   = (int*)alloc((size_t)NUM_GRAPHS * 4);
    int*    rowp   = (int*)alloc((size_t)(N_NODES + 1) * 4);
    int*    cursor = (int*)alloc((size_t)N_NODES * 4);
    int*    col    = (int*)alloc((size_t)N_EDGES * 4);
    float*  dinv   = (float*)alloc((size_t)N_NODES * 4);
    int*    csum   = (int*)alloc((size_t)NCHUNK * 4);
    int*    choff  = (int*)alloc((size_t)NCHUNK * 4);
    int*    goff   = (int*)alloc((size_t)(NUM_GRAPHS + 1) * 4);
    int*    gcur   = (int*)alloc((size_t)NUM_GRAPHS * 4);
    int*    nlist  = (int*)alloc((size_t)N_NODES * 4);
    float*  sums   = (float*)alloc((size_t)NUM_GRAPHS * HIDDEN * 4);
    ushort* Wp1    = (ushort*)alloc((size_t)16 * 4 * 64 * 8 * 2);
    ushort* Wp2    = (ushort*)alloc((size_t)16 * 8 * 64 * 8 * 2);
    ushort* Wp3    = (ushort*)alloc((size_t)16 * 8 * 64 * 8 * 2);
    ushort* Wp4    = (ushort*)alloc((size_t)16 * 8 * 64 * 8 * 2);
    ushort* bufA   = (ushort*)alloc((size_t)N_NODES * HIDDEN * 2);
    ushort* bufB   = (ushort*)alloc((size_t)N_NODES * HIDDEN * 2);

    hipMemsetAsync(cnt, 0, (size_t)N_NODES * 4, stream);
    hipMemsetAsync(gcnt, 0, (size_t)NUM_GRAPHS * 4, stream);

    const int* srcp = ei;
    const int* dstp = ei + N_EDGES;

    // CSR + degree + graph buckets
    k_count<<<(N_EDGES + 255) / 256, 256, 0, stream>>>(dstp, cnt);
    k_count_batch<<<(N_NODES + 255) / 256, 256, 0, stream>>>(batch, gcnt);
    k_chunksum<<<NCHUNK, 256, 0, stream>>>(cnt, csum);
    k_scanchunks<<<1, 256, 0, stream>>>(csum, choff);
    k_apply<<<NCHUNK, 256, 0, stream>>>(cnt, choff, rowp, cursor, dinv);
    k_fill<<<(N_EDGES + 255) / 256, 256, 0, stream>>>(srcp, dstp, cursor, col);
    k_scangraphs<<<1, NUM_GRAPHS, 0, stream>>>(gcnt, goff, gcur);
    k_fillg<<<(N_NODES + 255) / 256, 256, 0, stream>>>(batch, gcur, nlist);

    // weight repack (fp32 -> bf16 fragment layout)
    k_repackW<IN_FEAT><<<(16 * 4 * 64 + 255) / 256, 256, 0, stream>>>(W1, Wp1);
    k_repackW<HIDDEN><<<(16 * 8 * 64 + 255) / 256, 256, 0, stream>>>(Wsp + 0 * HIDDEN * HIDDEN, Wp2);
    k_repackW<HIDDEN><<<(16 * 8 * 64 + 255) / 256, 256, 0, stream>>>(Wsp + 1 * HIDDEN * HIDDEN, Wp3);
    k_repackW<HIDDEN><<<(16 * 8 * 64 + 255) / 256, 256, 0, stream>>>(Wsp + 2 * HIDDEN * HIDDEN, Wp4);

    const int GG = (N_NODES + 63) / 64;
    const int AGG_GRID = 2 * ((N_NODES + 3) / 4);

    // layer 1
    k_prescale<<<(N_NODES * IN_FEAT / 4 + 255) / 256, 256, 0, stream>>>(x, dinv, bufA);
    k_agg<IN_FEAT><<<AGG_GRID, 256, 0, stream>>>(bufA, col, rowp, dinv, bufB);
    k_mgemm<IN_FEAT, 0><<<GG, 256, 0, stream>>>(bufB, Wp1, b1, gamma, beta, rmean, rvar, dinv, bufA);

    // layers 2..3
    k_agg<HIDDEN><<<AGG_GRID, 256, 0, stream>>>(bufA, col, rowp, dinv, bufB);
    k_mgemm<HIDDEN, 1><<<GG, 256, 0, stream>>>(bufB, Wp2, bsp + 0 * HIDDEN,
                                               nullptr, nullptr, nullptr, nullptr, dinv, bufA);

    k_agg<HIDDEN><<<AGG_GRID, 256, 0, stream>>>(bufA, col, rowp, dinv, bufB);
    k_mgemm<HIDDEN, 1><<<GG, 256, 0, stream>>>(bufB, Wp3, bsp + 1 * HIDDEN,
                                               nullptr, nullptr, nullptr, nullptr, dinv, bufA);

    // layer 4 (plain relu, feeds pooling)
    k_agg<HIDDEN><<<AGG_GRID, 256, 0, stream>>>(bufA, col, rowp, dinv, bufB);
    k_mgemm<HIDDEN, 2><<<GG, 256, 0, stream>>>(bufB, Wp4, bsp + 2 * HIDDEN,
                                               nullptr, nullptr, nullptr, nullptr, dinv, bufA);

    k_pool2<<<NUM_GRAPHS * 2, 512, 0, stream>>>(bufA, nlist, goff, sums);
    k_logits<<<NUM_GRAPHS, 256, 0, stream>>>(sums, gcnt, W2, b2, out);
}